// Round 1
// baseline (241.965 us; speedup 1.0000x reference)
//
#include <hip/hip_runtime.h>

#define LSIG 4096
#define OUTL 8191      // 2L-1
#define OFF  520       // zero-pad each side (multiple of 8)
#define NPHYS 5312     // swizzled buffer words: sw(4096+2*520-1)=5295, rounded up
#define TT   8         // outputs per thread (consecutive t)

// additive swizzle: spreads stride-8 lane accesses over all 32 banks (2-way = free),
// keeps 8-aligned idx chunks contiguous in phys (no 32-boundary crossing)
__device__ __forceinline__ int sw(int x) { return x + (x >> 5); }

__global__ __launch_bounds__(256, 4)
void selfconv_kernel(const float* __restrict__ xg, float* __restrict__ outg) {
    __shared__ float buf[NPHYS];
    const int tid  = threadIdx.x;
    const int b    = blockIdx.x >> 2;   // 4 tile-blocks per batch
    const int tile = blockIdx.x & 3;
    const float* x = xg + b * LSIG;

    // zero-fill (pad regions + swizzle holes), then stage x at swizzled slots
    for (int p = tid; p < NPHYS; p += 256) buf[p] = 0.f;
    __syncthreads();
    for (int i = tid; i < LSIG; i += 256) buf[sw(i + OFF)] = x[i];
    __syncthreads();

    const int wave = tid >> 6;
    const int lane = tid & 63;
    const int tW = tile * 2048 + wave * 512;   // wave-tile of 512 outputs
    const int t0 = tW + lane * TT;             // this thread's first output

    // wave-uniform i-bounds covering all valid i for t in [tW, tW+511]
    int iLo = tW - (LSIG - 1); if (iLo < 0) iLo = 0;
    int iHi = tW + 511;        if (iHi > LSIG - 1) iHi = LSIG - 1;
    const int i0beg = iLo & ~7;
    const int iEnd  = (iHi + 8) & ~7;   // out-of-range i's read zero padding

    float acc[TT];
#pragma unroll
    for (int j = 0; j < TT; ++j) acc[j] = 0.f;

    // prime sliding window: w[j] = x[t0 + j - i0beg]
    float w[TT];
    {
        const int p = sw(t0 - i0beg + OFF);
#pragma unroll
        for (int j = 0; j < TT; ++j) w[j] = buf[p + j];
    }

    // preload first chunk: ac[k]=x[i0+k] (broadcast), nv[k]=x[t0-i0-8+k] (incoming window)
    float ac[8], nv[8];
    {
        const int pA = sw(i0beg + OFF);
        const int pW = sw(t0 - i0beg - 8 + OFF);
#pragma unroll
        for (int k = 0; k < 8; ++k) { ac[k] = buf[pA + k]; nv[k] = buf[pW + k]; }
    }

#pragma unroll 2
    for (int i0 = i0beg; i0 < iEnd; i0 += 8) {
        float ac2[8], nv2[8];
        const int i0n = i0 + 8;
        if (i0n < iEnd) {   // wave-uniform branch: 1-ahead software prefetch
            const int pA = sw(i0n + OFF);
            const int pW = sw(t0 - i0n - 8 + OFF);
#pragma unroll
            for (int k = 0; k < 8; ++k) { ac2[k] = buf[pA + k]; nv2[k] = buf[pW + k]; }
        } else {
#pragma unroll
            for (int k = 0; k < 8; ++k) { ac2[k] = 0.f; nv2[k] = 0.f; }
        }
#pragma unroll
        for (int k = 0; k < 8; ++k) {     // i = i0 + k
            const float a = ac[k];
#pragma unroll
            for (int j = 0; j < TT; ++j) acc[j] += a * w[j];
            // slide window down by one: w'[j] = x[t0+j-(i+1)]
#pragma unroll
            for (int j = TT - 1; j >= 1; --j) w[j] = w[j - 1];
            w[0] = nv[7 - k];
        }
#pragma unroll
        for (int k = 0; k < 8; ++k) { ac[k] = ac2[k]; nv[k] = nv2[k]; }
    }

    float* out = outg + b * OUTL + t0;
#pragma unroll
    for (int j = 0; j < TT; ++j) {
        if (t0 + j < OUTL) out[j] = acc[j];
    }
}

extern "C" void kernel_launch(void* const* d_in, const int* in_sizes, int n_in,
                              void* d_out, int out_size, void* d_ws, size_t ws_size,
                              hipStream_t stream) {
    const float* x = (const float*)d_in[0];
    float* out = (float*)d_out;
    // 128 batches x 4 tiles of 2048 outputs
    selfconv_kernel<<<dim3(128 * 4), dim3(256), 0, stream>>>(x, out);
}